// Round 2
// baseline (231.839 us; speedup 1.0000x reference)
//
#include <hip/hip_runtime.h>

// Proximity: mean over B of clipped L2 distance between L2-normalized x row
// and its label's L2-normalized center row.
// dist[i] = sxx/nx^2 + scc/nc^2 - 2*sxc/(nx*nc),  nx=max(sqrt(sxx),eps) etc.
//
// Fused single kernel: each block computes 4 samples (1 wave each), writes a
// per-block sum, and the last block to finish (device-scope atomic ticket)
// reduces the 4096 per-block sums to the mean. Counter is zeroed by a 4-byte
// hipMemsetAsync captured in the graph.

#define EPS_MIN 1e-12f
#define CLAMP_MAX 1e12f

typedef float v4f __attribute__((ext_vector_type(4)));

__global__ __launch_bounds__(256) void prox_fused_kernel(
    const float* __restrict__ x,
    const int* __restrict__ labels,
    const float* __restrict__ centers,
    float* __restrict__ partial,          // [gridDim.x] per-block sums
    unsigned int* __restrict__ counter,   // pre-zeroed ticket
    float* __restrict__ out,
    int Bn, int Dn, float inv_B)
{
    const int wave = threadIdx.x >> 6;
    const int lane = threadIdx.x & 63;
    const int sample = (blockIdx.x << 2) + wave;

    __shared__ float wsum[4];
    __shared__ unsigned int is_last;

    float dist = 0.0f;
    if (sample < Bn) {
        const float* xr = x + (size_t)sample * Dn;
        const int lbl = labels[sample];
        const float* cr = centers + (size_t)lbl * Dn;

        float sxx = 0.f, scc = 0.f, sxc = 0.f;
        if (Dn == 1024) {
            // 256 float4 per row, 64 lanes -> exactly 4 float4 per lane.
            // Plain cached loads (nt regressed -8% total in round 1).
            #pragma unroll
            for (int it = 0; it < 4; ++it) {
                const int idx = (lane + (it << 6)) << 2;
                v4f xv = *(const v4f*)(xr + idx);
                v4f cv = *(const v4f*)(cr + idx);
                sxx += xv[0] * xv[0] + xv[1] * xv[1] + xv[2] * xv[2] + xv[3] * xv[3];
                scc += cv[0] * cv[0] + cv[1] * cv[1] + cv[2] * cv[2] + cv[3] * cv[3];
                sxc += xv[0] * cv[0] + xv[1] * cv[1] + xv[2] * cv[2] + xv[3] * cv[3];
            }
        } else {
            #pragma unroll 4
            for (int f4 = lane; f4 * 4 < Dn; f4 += 64) {
                const int idx = f4 * 4;
                v4f xv = *(const v4f*)(xr + idx);
                v4f cv = *(const v4f*)(cr + idx);
                sxx += xv[0] * xv[0] + xv[1] * xv[1] + xv[2] * xv[2] + xv[3] * xv[3];
                scc += cv[0] * cv[0] + cv[1] * cv[1] + cv[2] * cv[2] + cv[3] * cv[3];
                sxc += xv[0] * cv[0] + xv[1] * cv[1] + xv[2] * cv[2] + xv[3] * cv[3];
            }
        }

        // 64-lane butterfly reduction (3 independent chains overlap).
        #pragma unroll
        for (int off = 32; off > 0; off >>= 1) {
            sxx += __shfl_down(sxx, off, 64);
            scc += __shfl_down(scc, off, 64);
            sxc += __shfl_down(sxc, off, 64);
        }
        if (lane == 0) {
            float nx = fmaxf(sqrtf(sxx), EPS_MIN);
            float nc = fmaxf(sqrtf(scc), EPS_MIN);
            float ixx = sxx / (nx * nx);   // (||x||/nx)^2, == 1 unless degenerate
            float icc = scc / (nc * nc);
            float dot = sxc / (nx * nc);
            float d = ixx + icc - 2.0f * dot;
            dist = fminf(fmaxf(d, EPS_MIN), CLAMP_MAX);
        }
    }
    if (lane == 0) wsum[wave] = dist;
    __syncthreads();

    if (threadIdx.x == 0) {
        partial[blockIdx.x] = wsum[0] + wsum[1] + wsum[2] + wsum[3];
        __threadfence();                      // release: publish partial
        unsigned int prev = atomicAdd(counter, 1u);   // device-scope
        is_last = (prev == gridDim.x - 1) ? 1u : 0u;
    }
    __syncthreads();

    if (is_last) {
        __threadfence();                      // acquire: see all partials
        const int n = gridDim.x;
        float s = 0.f;
        const int nv = n >> 2;
        const v4f* pv = (const v4f*)partial;
        for (int i = threadIdx.x; i < nv; i += 256) {
            v4f v = pv[i];
            s += (v[0] + v[1]) + (v[2] + v[3]);
        }
        for (int i = (nv << 2) + threadIdx.x; i < n; i += 256) s += partial[i];

        #pragma unroll
        for (int off = 32; off > 0; off >>= 1) s += __shfl_down(s, off, 64);
        __shared__ float smem[4];
        if (lane == 0) smem[wave] = s;
        __syncthreads();
        if (threadIdx.x == 0)
            out[0] = (smem[0] + smem[1] + smem[2] + smem[3]) * inv_B;
    }
}

extern "C" void kernel_launch(void* const* d_in, const int* in_sizes, int n_in,
                              void* d_out, int out_size, void* d_ws, size_t ws_size,
                              hipStream_t stream)
{
    const float* x       = (const float*)d_in[0];
    const int*   labels  = (const int*)d_in[1];
    const float* centers = (const float*)d_in[2];
    float* out = (float*)d_out;

    const int Bn = in_sizes[1];            // 16384
    const int Dn = in_sizes[0] / Bn;       // 1024

    const int blocks = (Bn + 3) / 4;       // 4096 blocks, 4 samples each
    float* partial = (float*)d_ws;         // blocks * 4 B = 16 KB
    unsigned int* counter = (unsigned int*)(partial + blocks);

    hipMemsetAsync((void*)counter, 0, sizeof(unsigned int), stream);
    prox_fused_kernel<<<blocks, 256, 0, stream>>>(x, labels, centers,
                                                  partial, counter, out,
                                                  Bn, Dn, 1.0f / (float)Bn);
}

// Round 3
// 100.373 us; speedup vs baseline: 2.3098x; 2.3098x over previous
//
#include <hip/hip_runtime.h>

// Proximity: mean over B of clipped L2 distance between L2-normalized x row
// and its label's L2-normalized center row.
// dist[i] = sxx/nx^2 + scc/nc^2 - 2*sxc/(nx*nc),  nx=max(sqrt(sxx),eps) etc.
//
// Two-kernel structure (round-2's last-block-done fusion regressed 2.3x:
// device-scope fence + single-address atomic serialize across non-coherent
// per-XCD L2s on gfx950 -- 136us even fully L3-warm).
//
// Partial kernel: 2 samples per wave, interleaved for ILP; no __syncthreads,
// no smem -- each wave writes one per-wave sum and retires independently.

#define EPS_MIN 1e-12f
#define CLAMP_MAX 1e12f

typedef float v4f __attribute__((ext_vector_type(4)));

__device__ __forceinline__ float finish_dist(float sxx, float scc, float sxc)
{
    float nx = fmaxf(sqrtf(sxx), EPS_MIN);
    float nc = fmaxf(sqrtf(scc), EPS_MIN);
    float ixx = sxx / (nx * nx);   // (||x||/nx)^2, == 1 unless degenerate
    float icc = scc / (nc * nc);
    float dot = sxc / (nx * nc);
    float d = ixx + icc - 2.0f * dot;
    return fminf(fmaxf(d, EPS_MIN), CLAMP_MAX);
}

__global__ __launch_bounds__(256) void prox_partial_kernel(
    const float* __restrict__ x,
    const int* __restrict__ labels,
    const float* __restrict__ centers,
    float* __restrict__ partial,        // [nwaves] per-wave (2-sample) sums
    int Bn, int Dn)
{
    const int wave = threadIdx.x >> 6;
    const int lane = threadIdx.x & 63;
    const int wid = (blockIdx.x << 2) + wave;   // global wave id
    const int s0 = wid << 1;
    const int s1 = s0 + 1;

    float sum = 0.0f;                   // valid on lane 0

    if (s1 < Bn) {
        // Common case: two samples, fully interleaved for load ILP.
        const float* xr0 = x + (size_t)s0 * Dn;
        const float* xr1 = x + (size_t)s1 * Dn;
        const float* cr0 = centers + (size_t)labels[s0] * Dn;
        const float* cr1 = centers + (size_t)labels[s1] * Dn;

        float sxx0 = 0.f, scc0 = 0.f, sxc0 = 0.f;
        float sxx1 = 0.f, scc1 = 0.f, sxc1 = 0.f;

        if (Dn == 1024) {
            // 256 float4 per row, 64 lanes -> 4 float4 per lane per sample.
            #pragma unroll
            for (int it = 0; it < 4; ++it) {
                const int idx = (lane + (it << 6)) << 2;
                v4f xv0 = *(const v4f*)(xr0 + idx);
                v4f cv0 = *(const v4f*)(cr0 + idx);
                v4f xv1 = *(const v4f*)(xr1 + idx);
                v4f cv1 = *(const v4f*)(cr1 + idx);
                sxx0 += xv0[0]*xv0[0] + xv0[1]*xv0[1] + xv0[2]*xv0[2] + xv0[3]*xv0[3];
                scc0 += cv0[0]*cv0[0] + cv0[1]*cv0[1] + cv0[2]*cv0[2] + cv0[3]*cv0[3];
                sxc0 += xv0[0]*cv0[0] + xv0[1]*cv0[1] + xv0[2]*cv0[2] + xv0[3]*cv0[3];
                sxx1 += xv1[0]*xv1[0] + xv1[1]*xv1[1] + xv1[2]*xv1[2] + xv1[3]*xv1[3];
                scc1 += cv1[0]*cv1[0] + cv1[1]*cv1[1] + cv1[2]*cv1[2] + cv1[3]*cv1[3];
                sxc1 += xv1[0]*cv1[0] + xv1[1]*cv1[1] + xv1[2]*cv1[2] + xv1[3]*cv1[3];
            }
        } else {
            #pragma unroll 2
            for (int f4 = lane; f4 * 4 < Dn; f4 += 64) {
                const int idx = f4 * 4;
                v4f xv0 = *(const v4f*)(xr0 + idx);
                v4f cv0 = *(const v4f*)(cr0 + idx);
                v4f xv1 = *(const v4f*)(xr1 + idx);
                v4f cv1 = *(const v4f*)(cr1 + idx);
                sxx0 += xv0[0]*xv0[0] + xv0[1]*xv0[1] + xv0[2]*xv0[2] + xv0[3]*xv0[3];
                scc0 += cv0[0]*cv0[0] + cv0[1]*cv0[1] + cv0[2]*cv0[2] + cv0[3]*cv0[3];
                sxc0 += xv0[0]*cv0[0] + xv0[1]*cv0[1] + xv0[2]*cv0[2] + xv0[3]*cv0[3];
                sxx1 += xv1[0]*xv1[0] + xv1[1]*xv1[1] + xv1[2]*xv1[2] + xv1[3]*xv1[3];
                scc1 += cv1[0]*cv1[0] + cv1[1]*cv1[1] + cv1[2]*cv1[2] + cv1[3]*cv1[3];
                sxc1 += xv1[0]*cv1[0] + xv1[1]*cv1[1] + xv1[2]*cv1[2] + xv1[3]*cv1[3];
            }
        }

        // 64-lane butterfly reduction (6 independent chains overlap).
        #pragma unroll
        for (int off = 32; off > 0; off >>= 1) {
            sxx0 += __shfl_down(sxx0, off, 64);
            scc0 += __shfl_down(scc0, off, 64);
            sxc0 += __shfl_down(sxc0, off, 64);
            sxx1 += __shfl_down(sxx1, off, 64);
            scc1 += __shfl_down(scc1, off, 64);
            sxc1 += __shfl_down(sxc1, off, 64);
        }
        if (lane == 0)
            sum = finish_dist(sxx0, scc0, sxc0) + finish_dist(sxx1, scc1, sxc1);
    } else if (s0 < Bn) {
        // Tail: single sample.
        const float* xr = x + (size_t)s0 * Dn;
        const float* cr = centers + (size_t)labels[s0] * Dn;
        float sxx = 0.f, scc = 0.f, sxc = 0.f;
        #pragma unroll 4
        for (int f4 = lane; f4 * 4 < Dn; f4 += 64) {
            const int idx = f4 * 4;
            v4f xv = *(const v4f*)(xr + idx);
            v4f cv = *(const v4f*)(cr + idx);
            sxx += xv[0]*xv[0] + xv[1]*xv[1] + xv[2]*xv[2] + xv[3]*xv[3];
            scc += cv[0]*cv[0] + cv[1]*cv[1] + cv[2]*cv[2] + cv[3]*cv[3];
            sxc += xv[0]*cv[0] + xv[1]*cv[1] + xv[2]*cv[2] + xv[3]*cv[3];
        }
        #pragma unroll
        for (int off = 32; off > 0; off >>= 1) {
            sxx += __shfl_down(sxx, off, 64);
            scc += __shfl_down(scc, off, 64);
            sxc += __shfl_down(sxc, off, 64);
        }
        if (lane == 0) sum = finish_dist(sxx, scc, sxc);
    }

    if (lane == 0) partial[wid] = sum;   // no cross-wave coupling, no barrier
}

// Single-block deterministic reduction of the per-wave sums -> mean.
__global__ __launch_bounds__(256) void prox_final_kernel(
    const float* __restrict__ partial, float* __restrict__ out,
    int n, float inv_B)
{
    float s = 0.f;
    const int nv = n >> 2;
    const v4f* pv = (const v4f*)partial;
    for (int i = threadIdx.x; i < nv; i += 256) {
        v4f v = pv[i];
        s += (v[0] + v[1]) + (v[2] + v[3]);
    }
    for (int i = (nv << 2) + threadIdx.x; i < n; i += 256) s += partial[i];

    __shared__ float smem[4];
    #pragma unroll
    for (int off = 32; off > 0; off >>= 1) s += __shfl_down(s, off, 64);
    const int wave = threadIdx.x >> 6;
    const int lane = threadIdx.x & 63;
    if (lane == 0) smem[wave] = s;
    __syncthreads();
    if (threadIdx.x == 0)
        out[0] = (smem[0] + smem[1] + smem[2] + smem[3]) * inv_B;
}

extern "C" void kernel_launch(void* const* d_in, const int* in_sizes, int n_in,
                              void* d_out, int out_size, void* d_ws, size_t ws_size,
                              hipStream_t stream)
{
    const float* x       = (const float*)d_in[0];
    const int*   labels  = (const int*)d_in[1];
    const float* centers = (const float*)d_in[2];
    float* out = (float*)d_out;

    const int Bn = in_sizes[1];            // 16384
    const int Dn = in_sizes[0] / Bn;       // 1024

    const int nwaves = (Bn + 1) / 2;       // 8192 waves, 2 samples each
    const int blocks = (nwaves + 3) / 4;   // 2048 blocks
    float* partial = (float*)d_ws;         // nwaves * 4 B = 32 KB

    prox_partial_kernel<<<blocks, 256, 0, stream>>>(x, labels, centers,
                                                    partial, Bn, Dn);
    prox_final_kernel<<<1, 256, 0, stream>>>(partial, out, nwaves,
                                             1.0f / (float)Bn);
}